// Round 9
// baseline (20.749 us; speedup 1.0000x reference)
//
#include <hip/hip_runtime.h>
#include <math.h>

#define H    1024
#define D2   2048    // input width of both big GEMVs
#define NB2  256     // blocks in kernel 2

typedef float f32x4 __attribute__((ext_vector_type(4)));

__device__ __forceinline__ float sigmoidf_(float x) {
    return 1.0f / (1.0f + expf(-x));
}

__device__ __forceinline__ float wave_sum(float v) {
#pragma unroll
    for (int off = 32; off >= 1; off >>= 1)
        v += __shfl_xor(v, off, 64);
    return v;
}

// Deep-prefetch GEMV core (R8, proven): load the wave's 3-row tile (24 f32x4)
// + x (8 f32x4) as one straight-line burst, then FMA, then wave-reduce.
__device__ __forceinline__ void gemv3_deep(
    const f32x4* __restrict__ x4,
    const f32x4* __restrict__ Wi,
    const f32x4* __restrict__ Wg,
    const f32x4* __restrict__ Wo,
    int lane, float& si, float& sg, float& so)
{
    f32x4 xv[8], wa[8], wg[8], wo[8];
#pragma unroll
    for (int it = 0; it < 8; ++it) xv[it] = x4[it * 64 + lane];
#pragma unroll
    for (int it = 0; it < 8; ++it) wa[it] = Wi[it * 64 + lane];
#pragma unroll
    for (int it = 0; it < 8; ++it) wg[it] = Wg[it * 64 + lane];
#pragma unroll
    for (int it = 0; it < 8; ++it) wo[it] = Wo[it * 64 + lane];

    float a = 0.f, b = 0.f, c = 0.f;
#pragma unroll
    for (int it = 0; it < 8; ++it) {
        a += wa[it].x * xv[it].x + wa[it].y * xv[it].y + wa[it].z * xv[it].z + wa[it].w * xv[it].w;
        b += wg[it].x * xv[it].x + wg[it].y * xv[it].y + wg[it].z * xv[it].z + wg[it].w * xv[it].w;
        c += wo[it].x * xv[it].x + wo[it].y * xv[it].y + wo[it].z * xv[it].z + wo[it].w * xv[it].w;
    }
    si = wave_sum(a);
    sg = wave_sum(b);
    so = wave_sum(c);
}

// Kernel 1: blocks 0..255 -> h_map (one wave per hidden j); block 256 -> h_pts
// and zeroes the fc ticket (kernel-boundary makes it visible to kernel 2).
__global__ __launch_bounds__(256, 1) void k_first(
    const float* __restrict__ x,       // map [2048]
    const float* __restrict__ W,       // W_ih_map [4096][2048]
    const float* __restrict__ b_ih,
    const float* __restrict__ b_hh,
    const float* __restrict__ Wp,      // W_ih_pts [4096][4]
    const float* __restrict__ bp_ih,
    const float* __restrict__ bp_hh,
    const float* __restrict__ goal,
    const float* __restrict__ cur,
    unsigned*    __restrict__ cnt,     // ws ticket (zeroed here each call)
    float* __restrict__ fin)           // ws: [0..1023]=h_map, [1024..2047]=h_pts
{
    int b = blockIdx.x;
    if (b < 256) {
        int wave = threadIdx.x >> 6;
        int lane = threadIdx.x & 63;
        int j = b * 4 + wave;
        float si, sg, so;
        gemv3_deep((const f32x4*)x,
                   (const f32x4*)(W + (size_t)j * D2),
                   (const f32x4*)(W + (size_t)(2 * H + j) * D2),
                   (const f32x4*)(W + (size_t)(3 * H + j) * D2),
                   lane, si, sg, so);
        if (lane == 0) {
            float gi = si + b_ih[j] + b_hh[j];
            float gg = sg + b_ih[2 * H + j] + b_hh[2 * H + j];
            float go = so + b_ih[3 * H + j] + b_hh[3 * H + j];
            float c = sigmoidf_(gi) * tanhf(gg);
            fin[j] = sigmoidf_(go) * tanhf(c);    // h_map[j]
        }
    } else {
        if (threadIdx.x == 0) {
            __hip_atomic_store(&cnt[0], 0u, __ATOMIC_RELAXED, __HIP_MEMORY_SCOPE_AGENT);
        }
        // points cell: points = [cur0, cur1, goal0, goal1]
        float p0 = cur[0], p1 = cur[1], p2 = goal[0], p3 = goal[1];
        const f32x4* Wp4 = (const f32x4*)Wp;     // one f32x4 per row
#pragma unroll
        for (int t = 0; t < 4; ++t) {
            int j = t * 256 + threadIdx.x;
            f32x4 wi = Wp4[j];
            f32x4 wg = Wp4[2 * H + j];
            f32x4 wo = Wp4[3 * H + j];
            float gi = wi.x * p0 + wi.y * p1 + wi.z * p2 + wi.w * p3 + bp_ih[j] + bp_hh[j];
            float gg = wg.x * p0 + wg.y * p1 + wg.z * p2 + wg.w * p3 + bp_ih[2 * H + j] + bp_hh[2 * H + j];
            float go = wo.x * p0 + wo.y * p1 + wo.z * p2 + wo.w * p3 + bp_ih[3 * H + j] + bp_hh[3 * H + j];
            float c = sigmoidf_(gi) * tanhf(gg);
            fin[H + j] = sigmoidf_(go) * tanhf(c);  // h_pts[j]
        }
    }
}

// Kernel 2: lstm1 cell + fence-free fc tail.
// Partials: relaxed agent atomic stores (write-through to coherence point,
// never dirty in L2). Ordering: one inline s_waitcnt vmcnt(0). Ticket:
// RELAXED fetch_add (bare fabric RMW — no buffer_wbl2, no invalidates).
// Winner block reads partials with relaxed agent loads. Zero fences.
__global__ __launch_bounds__(256, 1) void k_l1fc(
    const float* __restrict__ fin,     // ws [2048]
    const float* __restrict__ W1,      // W_ih_1 [4096][2048]
    const float* __restrict__ b1_i,
    const float* __restrict__ b1_h,
    const float* __restrict__ fcw,     // [2][1024]
    const float* __restrict__ fcb,     // [2]
    unsigned*    __restrict__ cnt,     // ws ticket (zeroed by k_first)
    float*       __restrict__ pbuf,    // ws: 512 floats
    float* __restrict__ out)           // [2]
{
    const int tid  = threadIdx.x;
    const int wave = tid >> 6;
    const int lane = tid & 63;
    const int j    = blockIdx.x * 4 + wave;

    __shared__ float    hs0[4], hs1[4];
    __shared__ unsigned slast;

    float si, sg, so;
    gemv3_deep((const f32x4*)fin,
               (const f32x4*)(W1 + (size_t)j * D2),
               (const f32x4*)(W1 + (size_t)(2 * H + j) * D2),
               (const f32x4*)(W1 + (size_t)(3 * H + j) * D2),
               lane, si, sg, so);
    if (lane == 0) {
        float gi = si + b1_i[j] + b1_h[j];
        float gg = sg + b1_i[2 * H + j] + b1_h[2 * H + j];
        float go = so + b1_i[3 * H + j] + b1_h[3 * H + j];
        float c = sigmoidf_(gi) * tanhf(gg);
        float h = sigmoidf_(go) * tanhf(c);     // h1[j]
        hs0[wave] = h * fcw[j];
        hs1[wave] = h * fcw[H + j];
    }
    __syncthreads();

    if (tid == 0) {
        float p0 = hs0[0] + hs0[1] + hs0[2] + hs0[3];
        float p1 = hs1[0] + hs1[1] + hs1[2] + hs1[3];
        __hip_atomic_store(&pbuf[2 * blockIdx.x],     p0, __ATOMIC_RELAXED, __HIP_MEMORY_SCOPE_AGENT);
        __hip_atomic_store(&pbuf[2 * blockIdx.x + 1], p1, __ATOMIC_RELAXED, __HIP_MEMORY_SCOPE_AGENT);
        asm volatile("s_waitcnt vmcnt(0)" ::: "memory");  // partials at coherence point
        unsigned old = __hip_atomic_fetch_add(&cnt[0], 1u, __ATOMIC_RELAXED, __HIP_MEMORY_SCOPE_AGENT);
        slast = (old == NB2 - 1) ? 1u : 0u;
    }
    __syncthreads();

    if (slast && wave == 0) {
        float s0 = 0.f, s1 = 0.f;
#pragma unroll
        for (int i = 0; i < 4; ++i) {
            int b = i * 64 + lane;
            s0 += __hip_atomic_load(&pbuf[2 * b],     __ATOMIC_RELAXED, __HIP_MEMORY_SCOPE_AGENT);
            s1 += __hip_atomic_load(&pbuf[2 * b + 1], __ATOMIC_RELAXED, __HIP_MEMORY_SCOPE_AGENT);
        }
        s0 = wave_sum(s0);
        s1 = wave_sum(s1);
        if (lane == 0) {
            out[0] = s0 + fcb[0];
            out[1] = s1 + fcb[1];
        }
    }
}

extern "C" void kernel_launch(void* const* d_in, const int* in_sizes, int n_in,
                              void* d_out, int out_size, void* d_ws, size_t ws_size,
                              hipStream_t stream) {
    const float* goal     = (const float*)d_in[0];
    const float* cur      = (const float*)d_in[1];
    const float* map      = (const float*)d_in[2];
    const float* W_ih_map = (const float*)d_in[3];
    // d_in[4] = W_hh_map  (unused: h0 = 0)
    const float* b_ih_map = (const float*)d_in[5];
    const float* b_hh_map = (const float*)d_in[6];
    const float* W_ih_pts = (const float*)d_in[7];
    // d_in[8] = W_hh_pts  (unused)
    const float* b_ih_pts = (const float*)d_in[9];
    const float* b_hh_pts = (const float*)d_in[10];
    const float* W_ih_1   = (const float*)d_in[11];
    // d_in[12] = W_hh_1   (unused)
    const float* b_ih_1   = (const float*)d_in[13];
    const float* b_hh_1   = (const float*)d_in[14];
    const float* fc_w     = (const float*)d_in[15];
    const float* fc_b     = (const float*)d_in[16];

    unsigned* cnt  = (unsigned*)d_ws;                  // ticket
    float*    pbuf = (float*)((char*)d_ws + 64);       // 512 floats
    float*    fin  = (float*)((char*)d_ws + 4096);     // 2048 floats
    float*    out  = (float*)d_out;

    k_first<<<257, 256, 0, stream>>>(map, W_ih_map, b_ih_map, b_hh_map,
                                     W_ih_pts, b_ih_pts, b_hh_pts,
                                     goal, cur, cnt, fin);
    k_l1fc<<<NB2, 256, 0, stream>>>(fin, W_ih_1, b_ih_1, b_hh_1,
                                    fc_w, fc_b, cnt, pbuf, out);
}